// Round 1
// baseline (132.348 us; speedup 1.0000x reference)
//
#include <hip/hip_runtime.h>
#include <hip/hip_bf16.h>

typedef __attribute__((ext_vector_type(8))) short bf16x8;
typedef __attribute__((ext_vector_type(4))) float f32x4;

typedef const __attribute__((address_space(1))) void* gptr_t;
typedef __attribute__((address_space(3))) void* lptr_t;

#define NROW 8192
#define DDIM 256
#define HALF_B 4096

// exp(dot/T) = exp2(dot * log2(e)/T), T = 0.07
#define E2SCALE 20.6099291555566196f
#define INV_T   14.2857142857142858f

// ---------------- kernel 1: row-normalize + bf16 cast ----------------
__global__ __launch_bounds__(64) void normalize_kernel(
    const float* __restrict__ z_i, const float* __restrict__ z_j,
    __hip_bfloat16* __restrict__ zn) {
  const int row = blockIdx.x;       // 0..8191
  const int lane = threadIdx.x;     // 0..63
  const float* src = (row < HALF_B) ? (z_i + (size_t)row * DDIM)
                                    : (z_j + (size_t)(row - HALF_B) * DDIM);
  float4 v = *reinterpret_cast<const float4*>(src + lane * 4);
  float ss = v.x * v.x + v.y * v.y + v.z * v.z + v.w * v.w;
#pragma unroll
  for (int m = 32; m; m >>= 1) ss += __shfl_xor(ss, m);
  float inv = 1.0f / sqrtf(ss);     // norms ~16, no clamp needed

  ushort4 o;
  {
    __hip_bfloat16 h;
    h = __float2bfloat16(v.x * inv); o.x = *reinterpret_cast<unsigned short*>(&h);
    h = __float2bfloat16(v.y * inv); o.y = *reinterpret_cast<unsigned short*>(&h);
    h = __float2bfloat16(v.z * inv); o.z = *reinterpret_cast<unsigned short*>(&h);
    h = __float2bfloat16(v.w * inv); o.w = *reinterpret_cast<unsigned short*>(&h);
  }
  *reinterpret_cast<ushort4*>(zn + (size_t)row * DDIM + lane * 4) = o;
}

// ---------------- kernel 2: tiled Gram + online exp-rowsum + pos ----------------
// 128x128 tile per block, 256 threads = 4 waves in 2x2, each wave 64x64 out.
__global__ __launch_bounds__(256) void gram_kernel(
    const __hip_bfloat16* __restrict__ zn,
    float* __restrict__ rowsum, float* __restrict__ pos) {
  __shared__ __hip_bfloat16 Asm[128 * 64];
  __shared__ __hip_bfloat16 Bsm[128 * 64];

  const int tid = threadIdx.x;
  const int lane = tid & 63;
  const int wid = tid >> 6;          // 0..3
  const int wr = wid >> 1;           // wave row 0..1
  const int wc = wid & 1;            // wave col 0..1
  const int rowBase = blockIdx.y * 128;
  const int colBase = blockIdx.x * 128;

  f32x4 acc[4][4] = {};

  for (int kt = 0; kt < 4; ++kt) {   // K = 256, BK = 64
    // ---- stage A and B tiles: 128x64 bf16 each = 16 KB, via global_load_lds x16B
#pragma unroll
    for (int t = 0; t < 4; ++t) {
      const int e = (t * 256 + tid) * 8;  // element index in [128][64] tile
      const int r = e >> 6;               // tile row
      const int c = e & 63;               // k within tile
      const __hip_bfloat16* ga = zn + (size_t)(rowBase + r) * DDIM + kt * 64 + c;
      const __hip_bfloat16* gb = zn + (size_t)(colBase + r) * DDIM + kt * 64 + c;
      // LDS dest: wave-uniform base; HW adds lane*16
      char* lA = reinterpret_cast<char*>(Asm) + t * 4096 + wid * 1024;
      char* lB = reinterpret_cast<char*>(Bsm) + t * 4096 + wid * 1024;
      __builtin_amdgcn_global_load_lds((gptr_t)ga, (lptr_t)lA, 16, 0, 0);
      __builtin_amdgcn_global_load_lds((gptr_t)gb, (lptr_t)lB, 16, 0, 0);
    }
    __syncthreads();

#pragma unroll
    for (int kk = 0; kk < 2; ++kk) {  // two k-steps of 32
      bf16x8 af[4], bfr[4];
      const int kcol = kk * 32 + (lane >> 4) * 8;
      const int arow = wr * 64 + (lane & 15);
      const int brow = wc * 64 + (lane & 15);
#pragma unroll
      for (int m = 0; m < 4; ++m)
        af[m] = *reinterpret_cast<const bf16x8*>(Asm + (arow + m * 16) * 64 + kcol);
#pragma unroll
      for (int n = 0; n < 4; ++n)
        bfr[n] = *reinterpret_cast<const bf16x8*>(Bsm + (brow + n * 16) * 64 + kcol);
#pragma unroll
      for (int m = 0; m < 4; ++m)
#pragma unroll
        for (int n = 0; n < 4; ++n)
          acc[m][n] = __builtin_amdgcn_mfma_f32_16x16x32_bf16(
              af[m], bfr[n], acc[m][n], 0, 0, 0);
    }
    __syncthreads();
  }

  // ---- epilogue: exp + row partial sums + pos extraction
  // C/D layout (verified m89/m91): col = lane&15, row = (lane>>4)*4 + v
#pragma unroll
  for (int m = 0; m < 4; ++m) {
#pragma unroll
    for (int v = 0; v < 4; ++v) {
      const int gi = rowBase + wr * 64 + m * 16 + (lane >> 4) * 4 + v;
      float partial = 0.0f;
#pragma unroll
      for (int n = 0; n < 4; ++n) {
        const int gj = colBase + wc * 64 + n * 16 + (lane & 15);
        const float d = acc[m][n][v];
        if (gj == (gi ^ HALF_B)) pos[gi] = d * INV_T;
        float val = exp2f(d * E2SCALE);
        if (gi == gj) val = 0.0f;   // exclude diagonal (predicate, no cancellation)
        partial += val;
      }
      // reduce across the 16 lanes sharing this gi
      partial += __shfl_xor(partial, 1);
      partial += __shfl_xor(partial, 2);
      partial += __shfl_xor(partial, 4);
      partial += __shfl_xor(partial, 8);
      if ((lane & 15) == 0) atomicAdd(&rowsum[gi], partial);
    }
  }
}

// ---------------- kernel 3: final loss reduction ----------------
__global__ __launch_bounds__(256) void loss_kernel(
    const float* __restrict__ rowsum, const float* __restrict__ pos,
    float* __restrict__ out) {
  __shared__ float sred[4];
  float s = 0.0f;
  for (int i = threadIdx.x; i < NROW; i += 256)
    s += logf(rowsum[i]) - pos[i];
#pragma unroll
  for (int m = 32; m; m >>= 1) s += __shfl_xor(s, m);
  if ((threadIdx.x & 63) == 0) sred[threadIdx.x >> 6] = s;
  __syncthreads();
  if (threadIdx.x == 0)
    out[0] = (sred[0] + sred[1] + sred[2] + sred[3]) / (float)NROW;
}

extern "C" void kernel_launch(void* const* d_in, const int* in_sizes, int n_in,
                              void* d_out, int out_size, void* d_ws, size_t ws_size,
                              hipStream_t stream) {
  const float* z_i = (const float*)d_in[0];
  const float* z_j = (const float*)d_in[1];
  float* out = (float*)d_out;

  char* ws = (char*)d_ws;
  __hip_bfloat16* zn = (__hip_bfloat16*)ws;                        // 4 MB
  float* rowsum = (float*)(ws + (size_t)NROW * DDIM * 2);          // 32 KB
  float* pos    = (float*)(ws + (size_t)NROW * DDIM * 2 + NROW * 4); // 32 KB

  hipMemsetAsync(rowsum, 0, NROW * sizeof(float), stream);
  normalize_kernel<<<NROW, 64, 0, stream>>>(z_i, z_j, zn);
  dim3 grid(NROW / 128, NROW / 128);
  gram_kernel<<<grid, 256, 0, stream>>>(zn, rowsum, pos);
  loss_kernel<<<1, 256, 0, stream>>>(rowsum, pos, out);
}

// Round 2
// 83.867 us; speedup vs baseline: 1.5781x; 1.5781x over previous
//
#include <hip/hip_runtime.h>
#include <hip/hip_bf16.h>

typedef __attribute__((ext_vector_type(8))) short bf16x8;
typedef __attribute__((ext_vector_type(4))) float f32x4;

typedef const __attribute__((address_space(1))) void* gptr_t;
typedef __attribute__((address_space(3))) void* lptr_t;

#define NROW 8192
#define DDIM 256
#define HALF_B 4096
#define NB 64            // 8192 / 128 tile blocks per side

// exp(dot/T) = exp2(dot * log2(e)/T), T = 0.07
#define E2SCALE 20.6099291555566196f
#define INV_T   14.2857142857142858f

// ---------------- kernel 1: row-normalize + bf16 cast ----------------
__global__ __launch_bounds__(64) void normalize_kernel(
    const float* __restrict__ z_i, const float* __restrict__ z_j,
    __hip_bfloat16* __restrict__ zn) {
  const int row = blockIdx.x;       // 0..8191
  const int lane = threadIdx.x;     // 0..63
  const float* src = (row < HALF_B) ? (z_i + (size_t)row * DDIM)
                                    : (z_j + (size_t)(row - HALF_B) * DDIM);
  float4 v = *reinterpret_cast<const float4*>(src + lane * 4);
  float ss = v.x * v.x + v.y * v.y + v.z * v.z + v.w * v.w;
#pragma unroll
  for (int m = 32; m; m >>= 1) ss += __shfl_xor(ss, m);
  float inv = 1.0f / sqrtf(ss);     // norms ~16, no clamp needed

  ushort4 o;
  {
    __hip_bfloat16 h;
    h = __float2bfloat16(v.x * inv); o.x = *reinterpret_cast<unsigned short*>(&h);
    h = __float2bfloat16(v.y * inv); o.y = *reinterpret_cast<unsigned short*>(&h);
    h = __float2bfloat16(v.z * inv); o.z = *reinterpret_cast<unsigned short*>(&h);
    h = __float2bfloat16(v.w * inv); o.w = *reinterpret_cast<unsigned short*>(&h);
  }
  *reinterpret_cast<ushort4*>(zn + (size_t)row * DDIM + lane * 4) = o;
}

// ---------------- kernel 2: upper-triangle tiled Gram + exp-sums + pos ------
// 128x128 tile per block, 256 threads = 4 waves in 2x2, each wave 64x64 out.
// LDS tiles XOR-swizzled (st-16B within 8-row stripes): linear gload_lds dest,
// pre-swizzled global source column, swizzled ds_read address.
__global__ __launch_bounds__(256) void gram_kernel(
    const __hip_bfloat16* __restrict__ zn,
    float* __restrict__ rowsum, float* __restrict__ pos) {
  __shared__ __hip_bfloat16 Asm[128 * 64];
  __shared__ __hip_bfloat16 Bsm[128 * 64];

  const int tid = threadIdx.x;
  const int lane = tid & 63;
  const int wid = tid >> 6;          // 0..3
  const int wr = wid >> 1;           // wave row 0..1
  const int wc = wid & 1;            // wave col 0..1

  // decode upper-triangle block index: row by has (NB - by) blocks
  int p = blockIdx.x;
  int by = 0;
  while (p >= NB - by) { p -= NB - by; ++by; }
  const int bx = by + p;
  const int rowBase = by * 128;
  const int colBase = bx * 128;
  const bool offdiag = (bx != by);

  f32x4 acc[4][4] = {};

  // pre-swizzled global source column (bytes within row handled in elements):
  // linear LDS write offset L = t*4096 + tid*16; r = L>>7; cswz elem =
  // ((tid&7) ^ ((tid>>3)&7)) * 8
  const int csw = ((tid & 7) ^ ((tid >> 3) & 7)) * 8;
  const int rloc = tid >> 3;   // row within 32-row chunk t

  for (int kt = 0; kt < 4; ++kt) {   // K = 256, BK = 64
#pragma unroll
    for (int t = 0; t < 4; ++t) {
      const int r = t * 32 + rloc;
      const __hip_bfloat16* ga = zn + (size_t)(rowBase + r) * DDIM + kt * 64 + csw;
      const __hip_bfloat16* gb = zn + (size_t)(colBase + r) * DDIM + kt * 64 + csw;
      char* lA = reinterpret_cast<char*>(Asm) + t * 4096 + wid * 1024;
      char* lB = reinterpret_cast<char*>(Bsm) + t * 4096 + wid * 1024;
      __builtin_amdgcn_global_load_lds((gptr_t)ga, (lptr_t)lA, 16, 0, 0);
      __builtin_amdgcn_global_load_lds((gptr_t)gb, (lptr_t)lB, 16, 0, 0);
    }
    __syncthreads();

    const char* Ab = reinterpret_cast<const char*>(Asm);
    const char* Bb = reinterpret_cast<const char*>(Bsm);
    const int xorv = (lane & 7) << 4;
#pragma unroll
    for (int kk = 0; kk < 2; ++kk) {  // two k-steps of 32
      bf16x8 af[4], bfr[4];
      const int kcolb = (kk * 32 + (lane >> 4) * 8) * 2;  // byte col
      const int arow = wr * 64 + (lane & 15);
      const int brow = wc * 64 + (lane & 15);
#pragma unroll
      for (int m = 0; m < 4; ++m)
        af[m] = *reinterpret_cast<const bf16x8*>(
            Ab + ((((arow + m * 16) << 7) + kcolb) ^ xorv));
#pragma unroll
      for (int n = 0; n < 4; ++n)
        bfr[n] = *reinterpret_cast<const bf16x8*>(
            Bb + ((((brow + n * 16) << 7) + kcolb) ^ xorv));
#pragma unroll
      for (int m = 0; m < 4; ++m)
#pragma unroll
        for (int n = 0; n < 4; ++n)
          acc[m][n] = __builtin_amdgcn_mfma_f32_16x16x32_bf16(
              af[m], bfr[n], acc[m][n], 0, 0, 0);
    }
    __syncthreads();
  }

  // ---- epilogue: exp + row AND column partial sums + pos extraction
  // C/D layout: col = lane&15, row = (lane>>4)*4 + v
  float colpart[4] = {0.0f, 0.0f, 0.0f, 0.0f};
#pragma unroll
  for (int m = 0; m < 4; ++m) {
#pragma unroll
    for (int v = 0; v < 4; ++v) {
      const int gi = rowBase + wr * 64 + m * 16 + (lane >> 4) * 4 + v;
      float rowpart = 0.0f;
#pragma unroll
      for (int n = 0; n < 4; ++n) {
        const int gj = colBase + wc * 64 + n * 16 + (lane & 15);
        const float d = acc[m][n][v];
        if (gj == gi + HALF_B) {       // pos pair (upper triangle only)
          const float pv = d * INV_T;
          pos[gi] = pv;
          pos[gj] = pv;
        }
        float val = exp2f(d * E2SCALE);
        if (gi == gj) val = 0.0f;      // exclude diagonal (predicate)
        rowpart += val;
        colpart[n] += val;
      }
      rowpart += __shfl_xor(rowpart, 1);
      rowpart += __shfl_xor(rowpart, 2);
      rowpart += __shfl_xor(rowpart, 4);
      rowpart += __shfl_xor(rowpart, 8);
      if ((lane & 15) == 0) atomicAdd(&rowsum[gi], rowpart);
    }
  }
  if (offdiag) {
    // symmetric contribution: column sums feed rowsum[gj]
#pragma unroll
    for (int n = 0; n < 4; ++n) {
      float c = colpart[n];
      c += __shfl_xor(c, 16);
      c += __shfl_xor(c, 32);
      if (lane < 16) {
        const int gj = colBase + wc * 64 + n * 16 + lane;
        atomicAdd(&rowsum[gj], c);
      }
    }
  }
}

// ---------------- kernel 3: final loss reduction ----------------
__global__ __launch_bounds__(256) void loss_kernel(
    const float* __restrict__ rowsum, const float* __restrict__ pos,
    float* __restrict__ out) {
  __shared__ float sred[4];
  float s = 0.0f;
  for (int i = threadIdx.x; i < NROW; i += 256)
    s += logf(rowsum[i]) - pos[i];
#pragma unroll
  for (int m = 32; m; m >>= 1) s += __shfl_xor(s, m);
  if ((threadIdx.x & 63) == 0) sred[threadIdx.x >> 6] = s;
  __syncthreads();
  if (threadIdx.x == 0)
    out[0] = (sred[0] + sred[1] + sred[2] + sred[3]) / (float)NROW;
}

extern "C" void kernel_launch(void* const* d_in, const int* in_sizes, int n_in,
                              void* d_out, int out_size, void* d_ws, size_t ws_size,
                              hipStream_t stream) {
  const float* z_i = (const float*)d_in[0];
  const float* z_j = (const float*)d_in[1];
  float* out = (float*)d_out;

  char* ws = (char*)d_ws;
  __hip_bfloat16* zn = (__hip_bfloat16*)ws;                          // 4 MB
  float* rowsum = (float*)(ws + (size_t)NROW * DDIM * 2);            // 32 KB
  float* pos    = (float*)(ws + (size_t)NROW * DDIM * 2 + NROW * 4); // 32 KB

  hipMemsetAsync(rowsum, 0, NROW * sizeof(float), stream);
  normalize_kernel<<<NROW, 64, 0, stream>>>(z_i, z_j, zn);
  const int nblocks = NB * (NB + 1) / 2;  // 2080 upper-triangle blocks
  gram_kernel<<<nblocks, 256, 0, stream>>>(zn, rowsum, pos);
  loss_kernel<<<1, 256, 0, stream>>>(rowsum, pos, out);
}

// Round 3
// 74.265 us; speedup vs baseline: 1.7821x; 1.1293x over previous
//
#include <hip/hip_runtime.h>
#include <hip/hip_bf16.h>

typedef __attribute__((ext_vector_type(8))) short bf16x8;
typedef __attribute__((ext_vector_type(4))) float f32x4;

typedef const __attribute__((address_space(1))) void* gptr_t;
typedef __attribute__((address_space(3))) void* lptr_t;

#define NROW 8192
#define DDIM 256
#define HALF_B 4096
#define NB2 32                      // 8192/256 tile blocks per side
#define NBLK (NB2 * (NB2 + 1) / 2)  // 528 upper-triangle blocks

// exp(dot/T) = exp2(dot * log2(e)/T), T = 0.07
#define E2SCALE 20.6099291555566196f
#define INV_T   14.2857142857142858f

// ---------------- kernel 1: row-normalize + bf16 cast + rowsum zero ---------
__global__ __launch_bounds__(256) void normalize_kernel(
    const float* __restrict__ z_i, const float* __restrict__ z_j,
    __hip_bfloat16* __restrict__ zn, float* __restrict__ rowsum) {
  const int lane = threadIdx.x & 63;
  const int row = blockIdx.x * 4 + (threadIdx.x >> 6);  // one row per wave
  const float* src = (row < HALF_B) ? (z_i + (size_t)row * DDIM)
                                    : (z_j + (size_t)(row - HALF_B) * DDIM);
  float4 v = *reinterpret_cast<const float4*>(src + lane * 4);
  float ss = v.x * v.x + v.y * v.y + v.z * v.z + v.w * v.w;
#pragma unroll
  for (int m = 32; m; m >>= 1) ss += __shfl_xor(ss, m);
  float inv = 1.0f / sqrtf(ss);

  ushort4 o;
  {
    __hip_bfloat16 h;
    h = __float2bfloat16(v.x * inv); o.x = *reinterpret_cast<unsigned short*>(&h);
    h = __float2bfloat16(v.y * inv); o.y = *reinterpret_cast<unsigned short*>(&h);
    h = __float2bfloat16(v.z * inv); o.z = *reinterpret_cast<unsigned short*>(&h);
    h = __float2bfloat16(v.w * inv); o.w = *reinterpret_cast<unsigned short*>(&h);
  }
  *reinterpret_cast<ushort4*>(zn + (size_t)row * DDIM + lane * 4) = o;
  if (lane == 0) rowsum[row] = 0.0f;
}

// ---------------- kernel 2: upper-triangle 256x256 Gram tiles ---------------
// 512 threads = 8 waves in 2x4; wave tile 128x64 (acc[8][4] of 16x16 frags).
// LDS double-buffered (2 x (A 32KB + B 32KB) = 128 KB); 2-phase pipeline:
// issue next-kt global_load_lds BEFORE computing current kt, one barrier/kt.
// XOR-swizzle (16B chunks within 8-row stripes) both sides: linear LDS dest,
// pre-swizzled global source column, swizzled ds_read byte address.
__global__ __launch_bounds__(512, 2) void gram_kernel(
    const __hip_bfloat16* __restrict__ zn,
    float* __restrict__ rowsum, float* __restrict__ pos) {
  __shared__ __hip_bfloat16 Asm[2 * 256 * 64];  // 64 KB (two 32 KB buffers)
  __shared__ __hip_bfloat16 Bsm[2 * 256 * 64];  // 64 KB

  const int tid = threadIdx.x;
  const int lane = tid & 63;
  const int wid = tid >> 6;          // 0..7
  const int wr = wid >> 2;           // wave row 0..1  (128 rows each)
  const int wc = wid & 3;            // wave col 0..3  (64 cols each)

  // decode upper-triangle block index: row-band by has (NB2 - by) blocks
  int p = blockIdx.x;
  int by = 0;
  while (p >= NB2 - by) { p -= NB2 - by; ++by; }
  const int bx = by + p;
  const int rowBase = by * 256;
  const int colBase = bx * 256;
  const bool offdiag = (bx != by);

  f32x4 acc[8][4] = {};

  // staging: per thread 16B; linear LDS offset (t*512+tid)*16 -> tile row
  // r = t*64 + (tid>>3); source column pre-swizzled within the 64-col K-slab
  const int csw = ((tid & 7) ^ ((tid >> 3) & 7)) * 8;
  const int rloc = tid >> 3;

  auto stage = [&](int kt, int buf) {
#pragma unroll
    for (int t = 0; t < 4; ++t) {
      const int r = t * 64 + rloc;
      const __hip_bfloat16* ga = zn + (size_t)(rowBase + r) * DDIM + kt * 64 + csw;
      const __hip_bfloat16* gb = zn + (size_t)(colBase + r) * DDIM + kt * 64 + csw;
      char* lA = reinterpret_cast<char*>(Asm) + buf * 32768 + t * 8192 + wid * 1024;
      char* lB = reinterpret_cast<char*>(Bsm) + buf * 32768 + t * 8192 + wid * 1024;
      __builtin_amdgcn_global_load_lds((gptr_t)ga, (lptr_t)lA, 16, 0, 0);
      __builtin_amdgcn_global_load_lds((gptr_t)gb, (lptr_t)lB, 16, 0, 0);
    }
  };

  // prologue: stage kt=0 into buf0
  stage(0, 0);
  __syncthreads();

  const int xorv = (lane & 7) << 4;
  for (int kt = 0; kt < 4; ++kt) {   // K = 256, BK = 64
    if (kt < 3) stage(kt + 1, (kt + 1) & 1);  // prefetch BEFORE compute

    const char* Ab = reinterpret_cast<const char*>(Asm) + (kt & 1) * 32768;
    const char* Bb = reinterpret_cast<const char*>(Bsm) + (kt & 1) * 32768;
#pragma unroll
    for (int kk = 0; kk < 2; ++kk) {
      bf16x8 af[8], bfr[4];
      const int kcolb = (kk * 32 + (lane >> 4) * 8) * 2;
#pragma unroll
      for (int m = 0; m < 8; ++m) {
        const int arow = wr * 128 + m * 16 + (lane & 15);
        af[m] = *reinterpret_cast<const bf16x8*>(
            Ab + (((arow << 7) + kcolb) ^ xorv));
      }
#pragma unroll
      for (int n = 0; n < 4; ++n) {
        const int brow = wc * 64 + n * 16 + (lane & 15);
        bfr[n] = *reinterpret_cast<const bf16x8*>(
            Bb + (((brow << 7) + kcolb) ^ xorv));
      }
#pragma unroll
      for (int m = 0; m < 8; ++m)
#pragma unroll
        for (int n = 0; n < 4; ++n)
          acc[m][n] = __builtin_amdgcn_mfma_f32_16x16x32_bf16(
              af[m], bfr[n], acc[m][n], 0, 0, 0);
    }
    __syncthreads();  // drains prefetch vmcnt (issued ~1000 cyc ago) + lgkm
  }

  // ---- epilogue: exp + row AND column partial sums + pos extraction
  // C/D layout: col = lane&15, row = (lane>>4)*4 + v
  float colpart[4] = {0.0f, 0.0f, 0.0f, 0.0f};
#pragma unroll
  for (int m = 0; m < 8; ++m) {
#pragma unroll
    for (int v = 0; v < 4; ++v) {
      const int gi = rowBase + wr * 128 + m * 16 + (lane >> 4) * 4 + v;
      float rowpart = 0.0f;
#pragma unroll
      for (int n = 0; n < 4; ++n) {
        const int gj = colBase + wc * 64 + n * 16 + (lane & 15);
        const float d = acc[m][n][v];
        if (gj == gi + HALF_B) {       // positive pair (upper triangle only)
          const float pv = d * INV_T;
          pos[gi] = pv;
          pos[gj] = pv;
        }
        float val = exp2f(d * E2SCALE);
        if (gi == gj) val = 0.0f;      // exclude diagonal (predicate)
        rowpart += val;
        colpart[n] += val;
      }
      rowpart += __shfl_xor(rowpart, 1);
      rowpart += __shfl_xor(rowpart, 2);
      rowpart += __shfl_xor(rowpart, 4);
      rowpart += __shfl_xor(rowpart, 8);
      if ((lane & 15) == 0) atomicAdd(&rowsum[gi], rowpart);
    }
  }
  if (offdiag) {
    // symmetric contribution: column sums feed rowsum[gj]
#pragma unroll
    for (int n = 0; n < 4; ++n) {
      float c = colpart[n];
      c += __shfl_xor(c, 16);
      c += __shfl_xor(c, 32);
      if (lane < 16) {
        const int gj = colBase + wc * 64 + n * 16 + lane;
        atomicAdd(&rowsum[gj], c);
      }
    }
  }
}

// ---------------- kernel 3: final loss reduction ----------------
__global__ __launch_bounds__(1024) void loss_kernel(
    const float* __restrict__ rowsum, const float* __restrict__ pos,
    float* __restrict__ out) {
  __shared__ float sred[16];
  float s = 0.0f;
  for (int i = threadIdx.x; i < NROW; i += 1024)
    s += logf(rowsum[i]) - pos[i];
#pragma unroll
  for (int m = 32; m; m >>= 1) s += __shfl_xor(s, m);
  if ((threadIdx.x & 63) == 0) sred[threadIdx.x >> 6] = s;
  __syncthreads();
  if (threadIdx.x < 16) {
    float t = sred[threadIdx.x];
#pragma unroll
    for (int m = 8; m; m >>= 1) t += __shfl_xor(t, m);
    if (threadIdx.x == 0) out[0] = t / (float)NROW;
  }
}

extern "C" void kernel_launch(void* const* d_in, const int* in_sizes, int n_in,
                              void* d_out, int out_size, void* d_ws, size_t ws_size,
                              hipStream_t stream) {
  const float* z_i = (const float*)d_in[0];
  const float* z_j = (const float*)d_in[1];
  float* out = (float*)d_out;

  char* ws = (char*)d_ws;
  __hip_bfloat16* zn = (__hip_bfloat16*)ws;                          // 4 MB
  float* rowsum = (float*)(ws + (size_t)NROW * DDIM * 2);            // 32 KB
  float* pos    = (float*)(ws + (size_t)NROW * DDIM * 2 + NROW * 4); // 32 KB

  normalize_kernel<<<NROW / 4, 256, 0, stream>>>(z_i, z_j, zn, rowsum);
  gram_kernel<<<NBLK, 512, 0, stream>>>(zn, rowsum, pos);
  loss_kernel<<<1, 1024, 0, stream>>>(rowsum, pos, out);
}